// Round 14
// baseline (781.723 us; speedup 1.0000x reference)
//
#include <hip/hip_runtime.h>
#include <math.h>

#define VOCAB 267735
#define NTOK  512
#define CDIV(a,b) (((a)+(b)-1)/(b))

typedef __bf16 bf16x8 __attribute__((ext_vector_type(8)));
typedef float f32x4 __attribute__((ext_vector_type(4)));
typedef const __attribute__((address_space(1))) void* gas_ptr;
typedef __attribute__((address_space(3))) void* las_ptr;

__device__ __forceinline__ unsigned short f2bf(float x) {
    unsigned int u = __float_as_uint(x);
    u = (u + 0x7FFFu + ((u >> 16) & 1u)) >> 16;
    return (unsigned short)u;
}
__device__ __forceinline__ float bf2f(unsigned short h) {
    return __uint_as_float(((unsigned int)h) << 16);
}
__device__ __forceinline__ void gload_lds16(const void* g, void* l) {
    __builtin_amdgcn_global_load_lds((gas_ptr)g, (las_ptr)l, 16, 0, 0);
}

// ---------------- hidden fp32 -> bf16 (only remaining conversion) ----------------
__global__ __launch_bounds__(256) void conv_h(
    const float* __restrict__ src, unsigned short* __restrict__ dst)
{
    int idx8 = blockIdx.x * 256 + threadIdx.x;   // 8 elems/thread, 512*1024 total
    const float* s = src + (size_t)idx8 * 8;
    float4 f0 = *(const float4*)s;
    float4 f1 = *(const float4*)(s + 4);
    ushort4 o0, o1;
    o0.x = f2bf(f0.x); o0.y = f2bf(f0.y); o0.z = f2bf(f0.z); o0.w = f2bf(f0.w);
    o1.x = f2bf(f1.x); o1.y = f2bf(f1.y); o1.z = f2bf(f1.z); o1.w = f2bf(f1.w);
    ushort4* d = (ushort4*)(dst + (size_t)idx8 * 8);
    d[0] = o0; d[1] = o1;
}

// ================= GEMM tile core: BM=BN=128, BK=32, single buffer ============
// A: bf16 [512][lda] via global_load_lds. B: fp32 [N][KB] reg-staged -> bf16
// (row clamp to N-1; kg>=KB zero-padded). K = loop extent (multiple of 32).
struct CDesc {
    const unsigned short* A;   // bf16
    const float* Bf;           // fp32 weights
    const float* bias;
    float* psum;
    unsigned short* L;         // bf16 out (proj Yo / head logit cache)
    float* Cout;
    int lda, KB, N, K, nx, pstride, ldL;
};
struct Descs { CDesc c[4]; int ofs[4]; };

// XCD-aware intra-cluster mapping (neutral r12, kept: harmless)
__device__ __forceinline__ void xcd_map(int local, int nx, int& bx, int& by)
{
    int q = nx >> 3, r = nx & 7;
    if (local < 32 * q) {
        bx = ((local >> 5) << 3) + (local & 7);
        by = (local >> 3) & 3;
    } else {
        int t = local - 32 * q;
        bx = (q << 3) + t % r;
        by = t / r;
    }
}

// MODE 0: L[gm*ldL+gn]=bf16(acc), gn<ldL
// MODE 1: psum[gm*pstride+2*bx+wn]=sum_{gn<N} exp(acc+bias); if L: L[..]=bf16(acc+bias)
// MODE 2: Cout[gm*VOCAB+gn]=acc+bias[gn]+adds[gm*4+ci]   (nontemporal)
template<int MODE>
__device__ __forceinline__ void gemm_tile(const CDesc& d, int bx, int by,
                                          const float* adds, int ci)
{
    __shared__ unsigned short As[128 * 32];
    __shared__ unsigned short Bs[128 * 32];
    const int tid  = threadIdx.x;
    const int lane = tid & 63;
    const int w    = tid >> 6;
    const int wm   = w >> 1, wn = w & 1;
    const int mBase = by * 128;
    const int nBase = bx * 128;
    const int col = lane & 15, rg = lane >> 4;

    f32x4 acc[4][4] = {};

    for (int k0 = 0; k0 < d.K; k0 += 32) {
        // A: 2 x 16B async loads into linear LDS [m][k]
        #pragma unroll
        for (int i = 0; i < 2; ++i) {
            int c = tid + i * 256;
            int m = c >> 2, k8 = (c & 3) * 8;
            gload_lds16(d.A + (size_t)(mBase + m) * d.lda + k0 + k8, &As[(size_t)c * 8]);
        }
        // B: reg-stage fp32 -> bf16 (validated round-4/5 pattern)
        #pragma unroll
        for (int i = 0; i < 4; ++i) {
            int c = tid + i * 256;               // 0..1023: 128 rows x 8 chunks(4 f32)
            int n = c >> 3, k = (c & 7) * 4;
            int gn = nBase + n; if (gn >= d.N) gn = d.N - 1;
            int kg = k0 + k;
            float4 f = make_float4(0.f, 0.f, 0.f, 0.f);
            if (kg < d.KB) f = *(const float4*)(d.Bf + (size_t)gn * d.KB + kg);
            ushort4 o;
            o.x = f2bf(f.x); o.y = f2bf(f.y); o.z = f2bf(f.z); o.w = f2bf(f.w);
            *(ushort4*)&Bs[n * 32 + k] = o;
        }
        __syncthreads();
        bf16x8 af[4], bfr[4];
        #pragma unroll
        for (int mi = 0; mi < 4; ++mi)
            af[mi] = *(const bf16x8*)&As[(wm * 64 + mi * 16 + col) * 32 + rg * 8];
        #pragma unroll
        for (int ni = 0; ni < 4; ++ni)
            bfr[ni] = *(const bf16x8*)&Bs[(wn * 64 + ni * 16 + col) * 32 + rg * 8];
        #pragma unroll
        for (int mi = 0; mi < 4; ++mi)
            #pragma unroll
            for (int ni = 0; ni < 4; ++ni)
                acc[mi][ni] = __builtin_amdgcn_mfma_f32_16x16x32_bf16(
                    af[mi], bfr[ni], acc[mi][ni], 0, 0, 0);
        __syncthreads();
    }

    if (MODE == 1) {
        const bool hasL = (d.L != nullptr);
        const int bx2 = bx * 2 + wn;
        #pragma unroll
        for (int mi = 0; mi < 4; ++mi) {
            int gm = mBase + wm * 64 + mi * 16 + rg * 4;
            float part[4] = {0.f, 0.f, 0.f, 0.f};
            #pragma unroll
            for (int ni = 0; ni < 4; ++ni) {
                int gn = nBase + wn * 64 + ni * 16 + col;
                float bvv = (gn < d.N) ? d.bias[gn] : 0.f;
                #pragma unroll
                for (int r = 0; r < 4; ++r) {
                    float v = acc[mi][ni][r] + bvv;
                    if (gn < d.N) part[r] += __expf(v);
                    if (hasL && gn < d.ldL)
                        d.L[(size_t)(gm + r) * d.ldL + gn] = f2bf(v);
                }
            }
            #pragma unroll
            for (int r = 0; r < 4; ++r) {
                float v = part[r];
                #pragma unroll
                for (int s = 8; s >= 1; s >>= 1) v += __shfl_xor(v, s, 16);
                if (col == 0)
                    d.psum[(size_t)(gm + r) * d.pstride + bx2] = v;
            }
        }
    } else if (MODE == 2) {
        #pragma unroll
        for (int mi = 0; mi < 4; ++mi) {
            int gm = mBase + wm * 64 + mi * 16 + rg * 4;
            float av[4];
            #pragma unroll
            for (int r = 0; r < 4; ++r) av[r] = adds[(gm + r) * 4 + ci];
            #pragma unroll
            for (int ni = 0; ni < 4; ++ni) {
                int gn = nBase + wn * 64 + ni * 16 + col;
                if (gn < d.N) {
                    float bvv = d.bias[gn];
                    #pragma unroll
                    for (int r = 0; r < 4; ++r)
                        __builtin_nontemporal_store(acc[mi][ni][r] + bvv + av[r],
                            &d.Cout[(size_t)(gm + r) * VOCAB + gn]);
                }
            }
        }
    } else {
        #pragma unroll
        for (int mi = 0; mi < 4; ++mi) {
            int gm = mBase + wm * 64 + mi * 16 + rg * 4;
            #pragma unroll
            for (int ni = 0; ni < 4; ++ni) {
                int gn = nBase + wn * 64 + ni * 16 + col;
                if (gn < d.ldL) {
                    #pragma unroll
                    for (int r = 0; r < 4; ++r)
                        d.L[(size_t)(gm + r) * d.ldL + gn] = f2bf(acc[mi][ni][r]);
                }
            }
        }
    }
}

__device__ __forceinline__ int decode_ci(const int* ofs, int bid) {
    int ci = 0;
    #pragma unroll
    for (int i = 1; i < 4; ++i) if (bid >= ofs[i]) ci = i;
    return ci;
}

// ---------------- cluster logits ----------------
__device__ __forceinline__ void hcl_block(
    const unsigned short* Y0b, const float* cw, const float* cb, float* hcl, int t)
{
    int w = threadIdx.x >> 6, l = threadIdx.x & 63;
    if (w >= 3) return;
    const unsigned short* yrow = Y0b + (size_t)t * 1024;
    float s = 0.f;
    #pragma unroll
    for (int e = 0; e < 16; ++e) {
        int k = l * 16 + e;
        s += bf2f(yrow[k]) * cw[w * 1024 + k];
    }
    #pragma unroll
    for (int off = 32; off > 0; off >>= 1) s += __shfl_down(s, off, 64);
    if (l == 0) hcl[t * 3 + w] = s + cb[w];
}

// ================= projections (48 blocks) ====================
__global__ __launch_bounds__(256) void proj_all(Descs PD)
{
    int bid = blockIdx.x;
    int ci = decode_ci(PD.ofs, bid);
    int local = bid - PD.ofs[ci];
    gemm_tile<0>(PD.c[ci], local % PD.c[ci].nx, local / PD.c[ci].nx, nullptr, ci);
}

// ================= stats: hcl (512) + 4 cluster GEMMs ====================
__global__ __launch_bounds__(256) void stats_all(
    Descs D, const unsigned short* __restrict__ Y0b,
    const float* __restrict__ cw, const float* __restrict__ cb,
    float* __restrict__ hcl)
{
    int bid = blockIdx.x;
    if (bid < NTOK) { hcl_block(Y0b, cw, cb, hcl, bid); return; }
    int b2 = bid - NTOK;
    int ci = decode_ci(D.ofs, b2);
    int local = b2 - D.ofs[ci];
    int bx, by;
    xcd_map(local, D.c[ci].nx, bx, by);
    gemm_tile<1>(D.c[ci], bx, by, nullptr, ci);
}

// ================= write: head apply + 3 tail GEMMs ====================
__global__ __launch_bounds__(256) void write_all(
    Descs D, const float* __restrict__ adds,
    const unsigned short* __restrict__ L0, float* __restrict__ out,
    int applyBlocks)
{
    int bid = blockIdx.x;
    if (bid < applyBlocks) {
        int idx8 = bid * 256 + threadIdx.x;
        int t = idx8 / 2500;
        int n = (idx8 % 2500) * 8;
        float a0 = adds[t * 4 + 0];
        ushort4 u0 = *(const ushort4*)(L0 + (size_t)t * 20096 + n);
        ushort4 u1 = *(const ushort4*)(L0 + (size_t)t * 20096 + n + 4);
        float* o = out + (size_t)t * VOCAB + n;
        f32x4 f0, f1;
        f0[0] = bf2f(u0.x) + a0; f0[1] = bf2f(u0.y) + a0;
        f0[2] = bf2f(u0.z) + a0; f0[3] = bf2f(u0.w) + a0;
        f1[0] = bf2f(u1.x) + a0; f1[1] = bf2f(u1.y) + a0;
        f1[2] = bf2f(u1.z) + a0; f1[3] = bf2f(u1.w) + a0;
        __builtin_nontemporal_store(f0, (f32x4*)o);
        __builtin_nontemporal_store(f1, (f32x4*)(o + 4));
        return;
    }
    int b2 = bid - applyBlocks;
    int ci = 1;
    #pragma unroll
    for (int i = 2; i < 4; ++i) if (b2 >= D.ofs[i]) ci = i;
    int local = b2 - D.ofs[ci];
    int bx, by;
    xcd_map(local, D.c[ci].nx, bx, by);
    gemm_tile<2>(D.c[ci], bx, by, adds, ci);
}

// ---------------- reduce partials + finish ----------------
__device__ __forceinline__ float blk_sum(float v, float* sm) {
    #pragma unroll
    for (int off = 32; off > 0; off >>= 1) v += __shfl_down(v, off, 64);
    int wid = threadIdx.x >> 6, lane = threadIdx.x & 63;
    if (lane == 0) sm[wid] = v;
    __syncthreads();
    float r = 0.f;
    if (threadIdx.x == 0) {
        for (int i = 0; i < 4; ++i) r += sm[i];
        sm[4] = r;
    }
    __syncthreads();
    r = sm[4];
    __syncthreads();
    return r;
}

__global__ __launch_bounds__(256) void reduce_finish(
    const float* __restrict__ p0, const float* __restrict__ p1,
    const float* __restrict__ p2, const float* __restrict__ p3,
    const float* __restrict__ hcl, float* __restrict__ adds,
    int n0, int n1, int n2, int n3)
{
    __shared__ float sm[8];
    const int t = blockIdx.x;
    const float* ps[4] = {p0 + (size_t)t * n0, p1 + (size_t)t * n1,
                          p2 + (size_t)t * n2, p3 + (size_t)t * n3};
    const int nn[4] = {n0, n1, n2, n3};
    float s[4];
    #pragma unroll
    for (int i = 0; i < 4; ++i) {
        float v = 0.f;
        for (int j = threadIdx.x; j < nn[i]; j += 256) v += ps[i][j];
        s[i] = blk_sum(v, sm);
    }
    if (threadIdx.x == 0) {
        float h0 = hcl[t * 3 + 0], h1 = hcl[t * 3 + 1], h2 = hcl[t * 3 + 2];
        float lse_head = __logf(s[0] + __expf(h0) + __expf(h1) + __expf(h2));
        adds[t * 4 + 0] = -lse_head;
        adds[t * 4 + 1] = (h0 - lse_head) - __logf(s[1]);
        adds[t * 4 + 2] = (h1 - lse_head) - __logf(s[2]);
        adds[t * 4 + 3] = (h2 - lse_head) - __logf(s[3]);
    }
}

// ---------------- loss ----------------
__global__ __launch_bounds__(512) void loss_kernel(
    const float* __restrict__ out, const int* __restrict__ target,
    float* __restrict__ loss)
{
    __shared__ float sm[8];
    const int t = threadIdx.x;
    float v = -out[(size_t)t * VOCAB + target[t]];
    #pragma unroll
    for (int off = 32; off > 0; off >>= 1) v += __shfl_down(v, off, 64);
    int wid = threadIdx.x >> 6, lane = threadIdx.x & 63;
    if (lane == 0) sm[wid] = v;
    __syncthreads();
    if (threadIdx.x == 0) {
        float s = 0.f;
        for (int i = 0; i < 8; ++i) s += sm[i];
        *loss = s / (float)NTOK;
    }
}

// ---------------- launch ----------------
extern "C" void kernel_launch(void* const* d_in, const int* in_sizes, int n_in,
                              void* d_out, int out_size, void* d_ws, size_t ws_size,
                              hipStream_t stream)
{
    const float* hidden = (const float*)d_in[0];
    const int*   target = (const int*)d_in[1];
    const float* cw     = (const float*)d_in[2];
    const float* cb     = (const float*)d_in[3];
    const float* proj[4] = {(const float*)d_in[4], (const float*)d_in[7],
                            (const float*)d_in[10], (const float*)d_in[13]};
    const float* W[4]    = {(const float*)d_in[5], (const float*)d_in[8],
                            (const float*)d_in[11], (const float*)d_in[14]};
    const float* b[4]    = {(const float*)d_in[6], (const float*)d_in[9],
                            (const float*)d_in[12], (const float*)d_in[15]};
    float* out = (float*)d_out;
    char*  w8  = (char*)d_ws;
    dim3 blk(256);

    const int nx0 = 157, nx1 = 157, nx2 = 1250, nx3 = 530;

    // ---- workspace layout (no weight arenas anymore) ----
    size_t off = 0;
    auto alloc = [&](size_t bytes) { size_t o = off; off += (bytes + 255) & ~(size_t)255; return o; };
    size_t oHb  = alloc((size_t)512 * 1024 * 2);
    size_t oY0  = alloc((size_t)512 * 1024 * 2);
    size_t oY1  = alloc((size_t)512 * 256 * 2);
    size_t oY2  = alloc((size_t)512 * 64 * 2);
    size_t oY3  = alloc((size_t)512 * 32 * 2);
    size_t ohcl = alloc((size_t)512 * 3 * 4);
    size_t oadd = alloc((size_t)512 * 4 * 4);
    size_t oL0  = alloc((size_t)512 * 20096 * 2);
    size_t oPS0 = alloc((size_t)512 * (2 * nx0) * 4);
    size_t oPS1 = alloc((size_t)512 * (2 * nx1) * 4);
    size_t oPS2 = alloc((size_t)512 * (2 * nx2) * 4);
    size_t oPS3 = alloc((size_t)512 * (2 * nx3) * 4);

    unsigned short* Hb  = (unsigned short*)(w8 + oHb);
    unsigned short* Y0b = (unsigned short*)(w8 + oY0);
    unsigned short* Y1b = (unsigned short*)(w8 + oY1);
    unsigned short* Y2b = (unsigned short*)(w8 + oY2);
    unsigned short* Y3p = (unsigned short*)(w8 + oY3);
    float* hcl  = (float*)(w8 + ohcl);
    float* adds = (float*)(w8 + oadd);
    unsigned short* L0 = (unsigned short*)(w8 + oL0);
    float* PS0  = (float*)(w8 + oPS0);
    float* PS1  = (float*)(w8 + oPS1);
    float* PS2  = (float*)(w8 + oPS2);
    float* PS3  = (float*)(w8 + oPS3);

    // ---- launch 1: convert hidden only (256 blocks) ----
    conv_h<<<256, blk, 0, stream>>>(hidden, Hb);

    // ---- launch 2: projections (48 blocks, B = proj fp32 reg-staged) ----
    Descs PD;
    PD.c[0] = {Hb, proj[0], nullptr, nullptr, Y0b, nullptr, 1024, 1024, 1024, 1024, 8, 0, 1024};
    PD.c[1] = {Hb, proj[1], nullptr, nullptr, Y1b, nullptr, 1024, 1024, 256,  1024, 2, 0, 256};
    PD.c[2] = {Hb, proj[2], nullptr, nullptr, Y2b, nullptr, 1024, 1024, 64,   1024, 1, 0, 64};
    PD.c[3] = {Hb, proj[3], nullptr, nullptr, Y3p, nullptr, 1024, 1024, 16,   1024, 1, 0, 32};
    PD.ofs[0] = 0; PD.ofs[1] = 32; PD.ofs[2] = 40; PD.ofs[3] = 44;
    proj_all<<<48, blk, 0, stream>>>(PD);

    // ---- launch 3: stats (hcl + 4 clusters; B = W fp32 reg-staged) ----
    Descs SD;
    SD.c[0] = {Y0b, W[0], b[0], PS0, L0,      nullptr, 1024, 1024, 20000,  1024, nx0, 2*nx0, 20096};
    SD.c[1] = {Y1b, W[1], b[1], PS1, nullptr, nullptr, 256,  256,  20000,  256,  nx1, 2*nx1, 0};
    SD.c[2] = {Y2b, W[2], b[2], PS2, nullptr, nullptr, 64,   64,   160000, 64,   nx2, 2*nx2, 0};
    SD.c[3] = {Y3p, W[3], b[3], PS3, nullptr, nullptr, 32,   16,   67735,  32,   nx3, 2*nx3, 0};
    SD.ofs[0] = 0; SD.ofs[1] = 4*nx0; SD.ofs[2] = 4*(nx0+nx1); SD.ofs[3] = 4*(nx0+nx1+nx2);
    stats_all<<<NTOK + 4*(nx0+nx1+nx2+nx3), blk, 0, stream>>>(SD, Y0b, cw, cb, hcl);

    // ---- launch 4: reduce + finish ----
    reduce_finish<<<NTOK, blk, 0, stream>>>(PS0, PS1, PS2, PS3, hcl, adds,
                                            2*nx0, 2*nx1, 2*nx2, 2*nx3);

    // ---- launch 5: write (head apply + tail GEMMs) ----
    Descs WD;
    WD.c[0] = SD.c[0];   // unused
    WD.c[1] = {Y1b, W[1], b[1], nullptr, nullptr, out + 20000,  256, 256, 20000,  256, nx1, 0, 0};
    WD.c[2] = {Y2b, W[2], b[2], nullptr, nullptr, out + 40000,  64,  64,  160000, 64,  nx2, 0, 0};
    WD.c[3] = {Y3p, W[3], b[3], nullptr, nullptr, out + 200000, 32,  16,  67735,  32,  nx3, 0, 0};
    WD.ofs[0] = 0; WD.ofs[1] = 0; WD.ofs[2] = 4*nx1; WD.ofs[3] = 4*(nx1+nx2);
    const int applyBlocks = 5000;
    write_all<<<applyBlocks + 4*(nx1+nx2+nx3), blk, 0, stream>>>(WD, adds, L0, out, applyBlocks);

    // ---- launch 6: loss ----
    loss_kernel<<<1, NTOK, 0, stream>>>(out, target, out + (size_t)NTOK * VOCAB);
}

// Round 15
// 480.086 us; speedup vs baseline: 1.6283x; 1.6283x over previous
//
#include <hip/hip_runtime.h>
#include <math.h>

#define VOCAB 267735
#define NTOK  512
#define CDIV(a,b) (((a)+(b)-1)/(b))

typedef __bf16 bf16x8 __attribute__((ext_vector_type(8)));
typedef float f32x4 __attribute__((ext_vector_type(4)));
typedef const __attribute__((address_space(1))) void* gas_ptr;
typedef __attribute__((address_space(3))) void* las_ptr;

__device__ __forceinline__ unsigned short f2bf(float x) {
    unsigned int u = __float_as_uint(x);
    u = (u + 0x7FFFu + ((u >> 16) & 1u)) >> 16;
    return (unsigned short)u;
}
__device__ __forceinline__ float bf2f(unsigned short h) {
    return __uint_as_float(((unsigned int)h) << 16);
}
__device__ __forceinline__ void gload_lds16(const void* g, void* l) {
    __builtin_amdgcn_global_load_lds((gas_ptr)g, (las_ptr)l, 16, 0, 0);
}

// ---------------- hidden fp32 -> bf16 (only conversion) ----------------
__global__ __launch_bounds__(256) void conv_h(
    const float* __restrict__ src, unsigned short* __restrict__ dst)
{
    int idx8 = blockIdx.x * 256 + threadIdx.x;   // 8 elems/thread, 512*1024 total
    const float* s = src + (size_t)idx8 * 8;
    float4 f0 = *(const float4*)s;
    float4 f1 = *(const float4*)(s + 4);
    ushort4 o0, o1;
    o0.x = f2bf(f0.x); o0.y = f2bf(f0.y); o0.z = f2bf(f0.z); o0.w = f2bf(f0.w);
    o1.x = f2bf(f1.x); o1.y = f2bf(f1.y); o1.z = f2bf(f1.z); o1.w = f2bf(f1.w);
    ushort4* d = (ushort4*)(dst + (size_t)idx8 * 8);
    d[0] = o0; d[1] = o1;
}

// ================= GEMM tile core: BM=BN=128, BK=32, single buffer ============
// A: bf16 [512][lda] via global_load_lds. B: fp32 [N][KB] reg-staged -> bf16
// (row clamp to N-1; kg>=KB zero-padded). K = loop extent (multiple of 32).
struct CDesc {
    const unsigned short* A;   // bf16
    const float* Bf;           // fp32 weights
    const float* bias;
    float* psum;
    unsigned short* L;         // bf16 out (proj Yo / head logit cache)
    float* Cout;
    int lda, KB, N, K, nx, pstride, ldL;
};
struct Descs { CDesc c[4]; int ofs[4]; };

// XCD-aware intra-cluster mapping (neutral r12, kept: harmless)
__device__ __forceinline__ void xcd_map(int local, int nx, int& bx, int& by)
{
    int q = nx >> 3, r = nx & 7;
    if (local < 32 * q) {
        bx = ((local >> 5) << 3) + (local & 7);
        by = (local >> 3) & 3;
    } else {
        int t = local - 32 * q;
        bx = (q << 3) + t % r;
        by = t / r;
    }
}

// MODE 0: L[gm*ldL+gn]=bf16(acc), gn<ldL
// MODE 1: psum[gm*pstride+2*bx+wn]=sum_{gn<N} exp(acc+bias); if L: L[..]=bf16(acc+bias)
// MODE 2: Cout[gm*VOCAB+gn]=acc+bias[gn]+adds[gm*4+ci]   (plain stores)
template<int MODE>
__device__ __forceinline__ void gemm_tile(const CDesc& d, int bx, int by,
                                          const float* adds, int ci)
{
    __shared__ unsigned short As[128 * 32];
    __shared__ unsigned short Bs[128 * 32];
    const int tid  = threadIdx.x;
    const int lane = tid & 63;
    const int w    = tid >> 6;
    const int wm   = w >> 1, wn = w & 1;
    const int mBase = by * 128;
    const int nBase = bx * 128;
    const int col = lane & 15, rg = lane >> 4;

    f32x4 acc[4][4] = {};

    for (int k0 = 0; k0 < d.K; k0 += 32) {
        // A: 2 x 16B async loads into linear LDS [m][k]
        #pragma unroll
        for (int i = 0; i < 2; ++i) {
            int c = tid + i * 256;
            int m = c >> 2, k8 = (c & 3) * 8;
            gload_lds16(d.A + (size_t)(mBase + m) * d.lda + k0 + k8, &As[(size_t)c * 8]);
        }
        // B: reg-stage fp32 -> bf16 (validated round-4/5 pattern)
        #pragma unroll
        for (int i = 0; i < 4; ++i) {
            int c = tid + i * 256;               // 0..1023: 128 rows x 8 chunks(4 f32)
            int n = c >> 3, k = (c & 7) * 4;
            int gn = nBase + n; if (gn >= d.N) gn = d.N - 1;
            int kg = k0 + k;
            float4 f = make_float4(0.f, 0.f, 0.f, 0.f);
            if (kg < d.KB) f = *(const float4*)(d.Bf + (size_t)gn * d.KB + kg);
            ushort4 o;
            o.x = f2bf(f.x); o.y = f2bf(f.y); o.z = f2bf(f.z); o.w = f2bf(f.w);
            *(ushort4*)&Bs[n * 32 + k] = o;
        }
        __syncthreads();
        bf16x8 af[4], bfr[4];
        #pragma unroll
        for (int mi = 0; mi < 4; ++mi)
            af[mi] = *(const bf16x8*)&As[(wm * 64 + mi * 16 + col) * 32 + rg * 8];
        #pragma unroll
        for (int ni = 0; ni < 4; ++ni)
            bfr[ni] = *(const bf16x8*)&Bs[(wn * 64 + ni * 16 + col) * 32 + rg * 8];
        #pragma unroll
        for (int mi = 0; mi < 4; ++mi)
            #pragma unroll
            for (int ni = 0; ni < 4; ++ni)
                acc[mi][ni] = __builtin_amdgcn_mfma_f32_16x16x32_bf16(
                    af[mi], bfr[ni], acc[mi][ni], 0, 0, 0);
        __syncthreads();
    }

    if (MODE == 1) {
        const bool hasL = (d.L != nullptr);
        const int bx2 = bx * 2 + wn;
        #pragma unroll
        for (int mi = 0; mi < 4; ++mi) {
            int gm = mBase + wm * 64 + mi * 16 + rg * 4;
            float part[4] = {0.f, 0.f, 0.f, 0.f};
            #pragma unroll
            for (int ni = 0; ni < 4; ++ni) {
                int gn = nBase + wn * 64 + ni * 16 + col;
                float bvv = (gn < d.N) ? d.bias[gn] : 0.f;
                #pragma unroll
                for (int r = 0; r < 4; ++r) {
                    float v = acc[mi][ni][r] + bvv;
                    if (gn < d.N) part[r] += __expf(v);
                    if (hasL && gn < d.ldL)
                        d.L[(size_t)(gm + r) * d.ldL + gn] = f2bf(v);
                }
            }
            #pragma unroll
            for (int r = 0; r < 4; ++r) {
                float v = part[r];
                #pragma unroll
                for (int s = 8; s >= 1; s >>= 1) v += __shfl_xor(v, s, 16);
                if (col == 0)
                    d.psum[(size_t)(gm + r) * d.pstride + bx2] = v;
            }
        }
    } else if (MODE == 2) {
        #pragma unroll
        for (int mi = 0; mi < 4; ++mi) {
            int gm = mBase + wm * 64 + mi * 16 + rg * 4;
            float av[4];
            #pragma unroll
            for (int r = 0; r < 4; ++r) av[r] = adds[(gm + r) * 4 + ci];
            #pragma unroll
            for (int ni = 0; ni < 4; ++ni) {
                int gn = nBase + wn * 64 + ni * 16 + col;
                if (gn < d.N) {
                    float bvv = d.bias[gn];
                    #pragma unroll
                    for (int r = 0; r < 4; ++r)
                        d.Cout[(size_t)(gm + r) * VOCAB + gn] = acc[mi][ni][r] + bvv + av[r];
                }
            }
        }
    } else {
        #pragma unroll
        for (int mi = 0; mi < 4; ++mi) {
            int gm = mBase + wm * 64 + mi * 16 + rg * 4;
            #pragma unroll
            for (int ni = 0; ni < 4; ++ni) {
                int gn = nBase + wn * 64 + ni * 16 + col;
                if (gn < d.ldL) {
                    #pragma unroll
                    for (int r = 0; r < 4; ++r)
                        d.L[(size_t)(gm + r) * d.ldL + gn] = f2bf(acc[mi][ni][r]);
                }
            }
        }
    }
}

__device__ __forceinline__ int decode_ci(const int* ofs, int bid) {
    int ci = 0;
    #pragma unroll
    for (int i = 1; i < 4; ++i) if (bid >= ofs[i]) ci = i;
    return ci;
}

// ---------------- cluster logits ----------------
__device__ __forceinline__ void hcl_block(
    const unsigned short* Y0b, const float* cw, const float* cb, float* hcl, int t)
{
    int w = threadIdx.x >> 6, l = threadIdx.x & 63;
    if (w >= 3) return;
    const unsigned short* yrow = Y0b + (size_t)t * 1024;
    float s = 0.f;
    #pragma unroll
    for (int e = 0; e < 16; ++e) {
        int k = l * 16 + e;
        s += bf2f(yrow[k]) * cw[w * 1024 + k];
    }
    #pragma unroll
    for (int off = 32; off > 0; off >>= 1) s += __shfl_down(s, off, 64);
    if (l == 0) hcl[t * 3 + w] = s + cb[w];
}

// ================= projections (48 blocks) ====================
__global__ __launch_bounds__(256) void proj_all(Descs PD)
{
    int bid = blockIdx.x;
    int ci = decode_ci(PD.ofs, bid);
    int local = bid - PD.ofs[ci];
    gemm_tile<0>(PD.c[ci], local % PD.c[ci].nx, local / PD.c[ci].nx, nullptr, ci);
}

// ================= stats: hcl (512) + 4 cluster GEMMs ====================
__global__ __launch_bounds__(256) void stats_all(
    Descs D, const unsigned short* __restrict__ Y0b,
    const float* __restrict__ cw, const float* __restrict__ cb,
    float* __restrict__ hcl)
{
    int bid = blockIdx.x;
    if (bid < NTOK) { hcl_block(Y0b, cw, cb, hcl, bid); return; }
    int b2 = bid - NTOK;
    int ci = decode_ci(D.ofs, b2);
    int local = b2 - D.ofs[ci];
    int bx, by;
    xcd_map(local, D.c[ci].nx, bx, by);
    gemm_tile<1>(D.c[ci], bx, by, nullptr, ci);
}

// ================= write: head apply + 3 tail GEMMs ====================
__global__ __launch_bounds__(256) void write_all(
    Descs D, const float* __restrict__ adds,
    const unsigned short* __restrict__ L0, float* __restrict__ out,
    int applyBlocks)
{
    int bid = blockIdx.x;
    if (bid < applyBlocks) {
        int idx8 = bid * 256 + threadIdx.x;
        int t = idx8 / 2500;
        int n = (idx8 % 2500) * 8;
        float a0 = adds[t * 4 + 0];
        ushort4 u0 = *(const ushort4*)(L0 + (size_t)t * 20096 + n);
        ushort4 u1 = *(const ushort4*)(L0 + (size_t)t * 20096 + n + 4);
        float* o = out + (size_t)t * VOCAB + n;
        float4 f0, f1;
        f0.x = bf2f(u0.x) + a0; f0.y = bf2f(u0.y) + a0;
        f0.z = bf2f(u0.z) + a0; f0.w = bf2f(u0.w) + a0;
        f1.x = bf2f(u1.x) + a0; f1.y = bf2f(u1.y) + a0;
        f1.z = bf2f(u1.z) + a0; f1.w = bf2f(u1.w) + a0;
        *(float4*)o = f0; *(float4*)(o + 4) = f1;
        return;
    }
    int b2 = bid - applyBlocks;
    int ci = 1;
    #pragma unroll
    for (int i = 2; i < 4; ++i) if (b2 >= D.ofs[i]) ci = i;
    int local = b2 - D.ofs[ci];
    int bx, by;
    xcd_map(local, D.c[ci].nx, bx, by);
    gemm_tile<2>(D.c[ci], bx, by, adds, ci);
}

// ---------------- reduce partials + finish ----------------
__device__ __forceinline__ float blk_sum(float v, float* sm) {
    #pragma unroll
    for (int off = 32; off > 0; off >>= 1) v += __shfl_down(v, off, 64);
    int wid = threadIdx.x >> 6, lane = threadIdx.x & 63;
    if (lane == 0) sm[wid] = v;
    __syncthreads();
    float r = 0.f;
    if (threadIdx.x == 0) {
        for (int i = 0; i < 4; ++i) r += sm[i];
        sm[4] = r;
    }
    __syncthreads();
    r = sm[4];
    __syncthreads();
    return r;
}

__global__ __launch_bounds__(256) void reduce_finish(
    const float* __restrict__ p0, const float* __restrict__ p1,
    const float* __restrict__ p2, const float* __restrict__ p3,
    const float* __restrict__ hcl, float* __restrict__ adds,
    int n0, int n1, int n2, int n3)
{
    __shared__ float sm[8];
    const int t = blockIdx.x;
    const float* ps[4] = {p0 + (size_t)t * n0, p1 + (size_t)t * n1,
                          p2 + (size_t)t * n2, p3 + (size_t)t * n3};
    const int nn[4] = {n0, n1, n2, n3};
    float s[4];
    #pragma unroll
    for (int i = 0; i < 4; ++i) {
        float v = 0.f;
        for (int j = threadIdx.x; j < nn[i]; j += 256) v += ps[i][j];
        s[i] = blk_sum(v, sm);
    }
    if (threadIdx.x == 0) {
        float h0 = hcl[t * 3 + 0], h1 = hcl[t * 3 + 1], h2 = hcl[t * 3 + 2];
        float lse_head = __logf(s[0] + __expf(h0) + __expf(h1) + __expf(h2));
        adds[t * 4 + 0] = -lse_head;
        adds[t * 4 + 1] = (h0 - lse_head) - __logf(s[1]);
        adds[t * 4 + 2] = (h1 - lse_head) - __logf(s[2]);
        adds[t * 4 + 3] = (h2 - lse_head) - __logf(s[3]);
    }
}

// ---------------- loss ----------------
__global__ __launch_bounds__(512) void loss_kernel(
    const float* __restrict__ out, const int* __restrict__ target,
    float* __restrict__ loss)
{
    __shared__ float sm[8];
    const int t = threadIdx.x;
    float v = -out[(size_t)t * VOCAB + target[t]];
    #pragma unroll
    for (int off = 32; off > 0; off >>= 1) v += __shfl_down(v, off, 64);
    int wid = threadIdx.x >> 6, lane = threadIdx.x & 63;
    if (lane == 0) sm[wid] = v;
    __syncthreads();
    if (threadIdx.x == 0) {
        float s = 0.f;
        for (int i = 0; i < 8; ++i) s += sm[i];
        *loss = s / (float)NTOK;
    }
}

// ---------------- launch ----------------
extern "C" void kernel_launch(void* const* d_in, const int* in_sizes, int n_in,
                              void* d_out, int out_size, void* d_ws, size_t ws_size,
                              hipStream_t stream)
{
    const float* hidden = (const float*)d_in[0];
    const int*   target = (const int*)d_in[1];
    const float* cw     = (const float*)d_in[2];
    const float* cb     = (const float*)d_in[3];
    const float* proj[4] = {(const float*)d_in[4], (const float*)d_in[7],
                            (const float*)d_in[10], (const float*)d_in[13]};
    const float* W[4]    = {(const float*)d_in[5], (const float*)d_in[8],
                            (const float*)d_in[11], (const float*)d_in[14]};
    const float* b[4]    = {(const float*)d_in[6], (const float*)d_in[9],
                            (const float*)d_in[12], (const float*)d_in[15]};
    float* out = (float*)d_out;
    char*  w8  = (char*)d_ws;
    dim3 blk(256);

    const int nx0 = 157, nx1 = 157, nx2 = 1250, nx3 = 530;

    // ---- workspace layout (no weight arenas) ----
    size_t off = 0;
    auto alloc = [&](size_t bytes) { size_t o = off; off += (bytes + 255) & ~(size_t)255; return o; };
    size_t oHb  = alloc((size_t)512 * 1024 * 2);
    size_t oY0  = alloc((size_t)512 * 1024 * 2);
    size_t oY1  = alloc((size_t)512 * 256 * 2);
    size_t oY2  = alloc((size_t)512 * 64 * 2);
    size_t oY3  = alloc((size_t)512 * 32 * 2);
    size_t ohcl = alloc((size_t)512 * 3 * 4);
    size_t oadd = alloc((size_t)512 * 4 * 4);
    size_t oL0  = alloc((size_t)512 * 20096 * 2);
    size_t oPS0 = alloc((size_t)512 * (2 * nx0) * 4);
    size_t oPS1 = alloc((size_t)512 * (2 * nx1) * 4);
    size_t oPS2 = alloc((size_t)512 * (2 * nx2) * 4);
    size_t oPS3 = alloc((size_t)512 * (2 * nx3) * 4);

    unsigned short* Hb  = (unsigned short*)(w8 + oHb);
    unsigned short* Y0b = (unsigned short*)(w8 + oY0);
    unsigned short* Y1b = (unsigned short*)(w8 + oY1);
    unsigned short* Y2b = (unsigned short*)(w8 + oY2);
    unsigned short* Y3p = (unsigned short*)(w8 + oY3);
    float* hcl  = (float*)(w8 + ohcl);
    float* adds = (float*)(w8 + oadd);
    unsigned short* L0 = (unsigned short*)(w8 + oL0);
    float* PS0  = (float*)(w8 + oPS0);
    float* PS1  = (float*)(w8 + oPS1);
    float* PS2  = (float*)(w8 + oPS2);
    float* PS3  = (float*)(w8 + oPS3);

    // ---- launch 1: convert hidden only (256 blocks) ----
    conv_h<<<256, blk, 0, stream>>>(hidden, Hb);

    // ---- launch 2: projections (48 blocks, B = proj fp32 reg-staged) ----
    Descs PD;
    PD.c[0] = {Hb, proj[0], nullptr, nullptr, Y0b, nullptr, 1024, 1024, 1024, 1024, 8, 0, 1024};
    PD.c[1] = {Hb, proj[1], nullptr, nullptr, Y1b, nullptr, 1024, 1024, 256,  1024, 2, 0, 256};
    PD.c[2] = {Hb, proj[2], nullptr, nullptr, Y2b, nullptr, 1024, 1024, 64,   1024, 1, 0, 64};
    PD.c[3] = {Hb, proj[3], nullptr, nullptr, Y3p, nullptr, 1024, 1024, 16,   1024, 1, 0, 32};
    PD.ofs[0] = 0; PD.ofs[1] = 32; PD.ofs[2] = 40; PD.ofs[3] = 44;
    proj_all<<<48, blk, 0, stream>>>(PD);

    // ---- launch 3: stats (hcl + 4 clusters; B = W fp32 reg-staged) ----
    Descs SD;
    SD.c[0] = {Y0b, W[0], b[0], PS0, L0,      nullptr, 1024, 1024, 20000,  1024, nx0, 2*nx0, 20096};
    SD.c[1] = {Y1b, W[1], b[1], PS1, nullptr, nullptr, 256,  256,  20000,  256,  nx1, 2*nx1, 0};
    SD.c[2] = {Y2b, W[2], b[2], PS2, nullptr, nullptr, 64,   64,   160000, 64,   nx2, 2*nx2, 0};
    SD.c[3] = {Y3p, W[3], b[3], PS3, nullptr, nullptr, 32,   16,   67735,  32,   nx3, 2*nx3, 0};
    SD.ofs[0] = 0; SD.ofs[1] = 4*nx0; SD.ofs[2] = 4*(nx0+nx1); SD.ofs[3] = 4*(nx0+nx1+nx2);
    stats_all<<<NTOK + 4*(nx0+nx1+nx2+nx3), blk, 0, stream>>>(SD, Y0b, cw, cb, hcl);

    // ---- launch 4: reduce + finish ----
    reduce_finish<<<NTOK, blk, 0, stream>>>(PS0, PS1, PS2, PS3, hcl, adds,
                                            2*nx0, 2*nx1, 2*nx2, 2*nx3);

    // ---- launch 5: write (head apply + tail GEMMs) ----
    Descs WD;
    WD.c[0] = SD.c[0];   // unused
    WD.c[1] = {Y1b, W[1], b[1], nullptr, nullptr, out + 20000,  256, 256, 20000,  256, nx1, 0, 0};
    WD.c[2] = {Y2b, W[2], b[2], nullptr, nullptr, out + 40000,  64,  64,  160000, 64,  nx2, 0, 0};
    WD.c[3] = {Y3p, W[3], b[3], nullptr, nullptr, out + 200000, 32,  16,  67735,  32,  nx3, 0, 0};
    WD.ofs[0] = 0; WD.ofs[1] = 0; WD.ofs[2] = 4*nx1; WD.ofs[3] = 4*(nx1+nx2);
    const int applyBlocks = 5000;
    write_all<<<applyBlocks + 4*(nx1+nx2+nx3), blk, 0, stream>>>(WD, adds, L0, out, applyBlocks);

    // ---- launch 6: loss ----
    loss_kernel<<<1, NTOK, 0, stream>>>(out, target, out + (size_t)NTOK * VOCAB);
}

// Round 16
// 394.454 us; speedup vs baseline: 1.9818x; 1.2171x over previous
//
#include <hip/hip_runtime.h>
#include <math.h>

#define VOCAB 267735
#define NTOK  512
#define CDIV(a,b) (((a)+(b)-1)/(b))
#define BIGSTART 0x7fffffff

typedef __bf16 bf16x8 __attribute__((ext_vector_type(8)));
typedef float f32x4 __attribute__((ext_vector_type(4)));
typedef const __attribute__((address_space(1))) void* gas_ptr;
typedef __attribute__((address_space(3))) void* las_ptr;

__device__ __forceinline__ unsigned short f2bf(float x) {
    unsigned int u = __float_as_uint(x);
    u = (u + 0x7FFFu + ((u >> 16) & 1u)) >> 16;
    return (unsigned short)u;
}
__device__ __forceinline__ float bf2f(unsigned short h) {
    return __uint_as_float(((unsigned int)h) << 16);
}
__device__ __forceinline__ void gload_lds16(const void* g, void* l) {
    __builtin_amdgcn_global_load_lds((gas_ptr)g, (las_ptr)l, 16, 0, 0);
}

// ================= fp32->bf16 conversion block (shared device body) =================
struct ConvDesc { const float* src; unsigned short* dst; int nrows, kb, npad, ldb; };
struct Conv9 { ConvDesc d[9]; int start[9]; };

__device__ __forceinline__ void conv_block(const Conv9& C, int bid)
{
    int i = 8;
    #pragma unroll
    for (int k = 8; k >= 1; --k) if (bid < C.start[k]) i = k - 1;
    const ConvDesc d = C.d[i];
    int local = bid - C.start[i];
    int idx8 = local * 256 + threadIdx.x;
    int ld8 = d.ldb / 8;
    int r  = idx8 / ld8;
    int c8 = (idx8 % ld8) * 8;
    ushort4 o0 = {0,0,0,0}, o1 = {0,0,0,0};
    if (r < d.nrows && c8 < d.kb) {
        const float* s = d.src + (size_t)r * d.kb + c8;
        float4 f0 = *(const float4*)s;
        float4 f1 = *(const float4*)(s + 4);
        o0.x = f2bf(f0.x); o0.y = f2bf(f0.y); o0.z = f2bf(f0.z); o0.w = f2bf(f0.w);
        o1.x = f2bf(f1.x); o1.y = f2bf(f1.y); o1.z = f2bf(f1.z); o1.w = f2bf(f1.w);
    }
    ushort4* dd = (ushort4*)(d.dst + (size_t)r * d.ldb + c8);
    dd[0] = o0; dd[1] = o1;
}

__global__ __launch_bounds__(256) void conv_all(Conv9 C) { conv_block(C, blockIdx.x); }

// ================= GEMM tile core (r12 validated: BM=BN=128, BK=32, single buffer) =====
struct CDesc {
    const unsigned short* A;   // [512][lda] bf16
    const unsigned short* Bb;  // [Npad][ldb] bf16 arena, pads zero
    const float* bias;
    float* psum;
    unsigned short* L;         // bf16 logit cache (nullable)
    float* Cout;
    int lda, ldb, N, K, nx, pstride, ldL;
};
struct Descs { CDesc c[4]; int ofs[4]; };

// XCD-aware intra-cluster mapping (neutral, harmless)
__device__ __forceinline__ void xcd_map(int local, int nx, int& bx, int& by)
{
    int q = nx >> 3, r = nx & 7;
    if (local < 32 * q) {
        bx = ((local >> 5) << 3) + (local & 7);
        by = (local >> 3) & 3;
    } else {
        int t = local - 32 * q;
        bx = (q << 3) + t % r;
        by = t / r;
    }
}

// MODE 0: L[gm*ldL+gn]=bf16(acc), gn<ldL
// MODE 1: psum[gm*pstride+2*bx+wn]=sum_{gn<N} exp(acc+bias); if L: L[..]=bf16(acc+bias)
// MODE 2: Cout[gm*VOCAB+gn]=acc+bias[gn]+adds[gm*4+ci]
template<int MODE>
__device__ __forceinline__ void gemm_tile(const CDesc& d, int bx, int by,
                                          const float* adds, int ci)
{
    __shared__ unsigned short As[128 * 32];
    __shared__ unsigned short Bs[128 * 32];
    const int tid  = threadIdx.x;
    const int lane = tid & 63;
    const int w    = tid >> 6;
    const int wm   = w >> 1, wn = w & 1;
    const int mBase = by * 128;
    const int nBase = bx * 128;
    const int col = lane & 15, rg = lane >> 4;

    f32x4 acc[4][4] = {};

    for (int k0 = 0; k0 < d.K; k0 += 32) {
        #pragma unroll
        for (int i = 0; i < 2; ++i) {
            int c = tid + i * 256;
            int m = c >> 2, k8 = (c & 3) * 8;
            gload_lds16(d.A + (size_t)(mBase + m) * d.lda + k0 + k8, &As[(size_t)c * 8]);
        }
        #pragma unroll
        for (int i = 0; i < 2; ++i) {
            int c = tid + i * 256;
            int n = c >> 2, k8 = (c & 3) * 8;
            gload_lds16(d.Bb + (size_t)(nBase + n) * d.ldb + k0 + k8, &Bs[(size_t)c * 8]);
        }
        __syncthreads();
        bf16x8 af[4], bfr[4];
        #pragma unroll
        for (int mi = 0; mi < 4; ++mi)
            af[mi] = *(const bf16x8*)&As[(wm * 64 + mi * 16 + col) * 32 + rg * 8];
        #pragma unroll
        for (int ni = 0; ni < 4; ++ni)
            bfr[ni] = *(const bf16x8*)&Bs[(wn * 64 + ni * 16 + col) * 32 + rg * 8];
        #pragma unroll
        for (int mi = 0; mi < 4; ++mi)
            #pragma unroll
            for (int ni = 0; ni < 4; ++ni)
                acc[mi][ni] = __builtin_amdgcn_mfma_f32_16x16x32_bf16(
                    af[mi], bfr[ni], acc[mi][ni], 0, 0, 0);
        __syncthreads();
    }

    if (MODE == 1) {
        const bool hasL = (d.L != nullptr);
        const int bx2 = bx * 2 + wn;
        #pragma unroll
        for (int mi = 0; mi < 4; ++mi) {
            int gm = mBase + wm * 64 + mi * 16 + rg * 4;
            float part[4] = {0.f, 0.f, 0.f, 0.f};
            #pragma unroll
            for (int ni = 0; ni < 4; ++ni) {
                int gn = nBase + wn * 64 + ni * 16 + col;
                float bvv = (gn < d.N) ? d.bias[gn] : 0.f;
                #pragma unroll
                for (int r = 0; r < 4; ++r) {
                    float v = acc[mi][ni][r] + bvv;
                    if (gn < d.N) part[r] += __expf(v);
                    if (hasL) d.L[(size_t)(gm + r) * d.ldL + gn] = f2bf(v);
                }
            }
            #pragma unroll
            for (int r = 0; r < 4; ++r) {
                float v = part[r];
                #pragma unroll
                for (int s = 8; s >= 1; s >>= 1) v += __shfl_xor(v, s, 16);
                if (col == 0)
                    d.psum[(size_t)(gm + r) * d.pstride + bx2] = v;
            }
        }
    } else if (MODE == 2) {
        #pragma unroll
        for (int mi = 0; mi < 4; ++mi) {
            int gm = mBase + wm * 64 + mi * 16 + rg * 4;
            float av[4];
            #pragma unroll
            for (int r = 0; r < 4; ++r) av[r] = adds[(gm + r) * 4 + ci];
            #pragma unroll
            for (int ni = 0; ni < 4; ++ni) {
                int gn = nBase + wn * 64 + ni * 16 + col;
                if (gn < d.N) {
                    float bvv = d.bias[gn];
                    #pragma unroll
                    for (int r = 0; r < 4; ++r)
                        d.Cout[(size_t)(gm + r) * VOCAB + gn] = acc[mi][ni][r] + bvv + av[r];
                }
            }
        }
    } else {
        #pragma unroll
        for (int mi = 0; mi < 4; ++mi) {
            int gm = mBase + wm * 64 + mi * 16 + rg * 4;
            #pragma unroll
            for (int ni = 0; ni < 4; ++ni) {
                int gn = nBase + wn * 64 + ni * 16 + col;
                if (gn < d.ldL) {
                    #pragma unroll
                    for (int r = 0; r < 4; ++r)
                        d.L[(size_t)(gm + r) * d.ldL + gn] = f2bf(acc[mi][ni][r]);
                }
            }
        }
    }
}

__device__ __forceinline__ int decode_ci(const int* ofs, int bid) {
    int ci = 0;
    #pragma unroll
    for (int i = 1; i < 4; ++i) if (bid >= ofs[i]) ci = i;
    return ci;
}

// ---------------- cluster logits ----------------
__device__ __forceinline__ void hcl_block(
    const unsigned short* Y0b, const float* cw, const float* cb, float* hcl, int t)
{
    int w = threadIdx.x >> 6, l = threadIdx.x & 63;
    if (w >= 3) return;
    const unsigned short* yrow = Y0b + (size_t)t * 1024;
    float s = 0.f;
    #pragma unroll
    for (int e = 0; e < 16; ++e) {
        int k = l * 16 + e;
        s += bf2f(yrow[k]) * cw[w * 1024 + k];
    }
    #pragma unroll
    for (int off = 32; off > 0; off >>= 1) s += __shfl_down(s, off, 64);
    if (l == 0) hcl[t * 3 + w] = s + cb[w];
}

// ================= mega launch: proj GEMMs (48) + W conversion =========
__global__ __launch_bounds__(256) void mega_projconv(Descs PD, Conv9 CW)
{
    int bid = blockIdx.x;
    if (bid < 48) {
        int ci = decode_ci(PD.ofs, bid);
        int local = bid - PD.ofs[ci];
        gemm_tile<0>(PD.c[ci], local % PD.c[ci].nx, local / PD.c[ci].nx, nullptr, ci);
        return;
    }
    conv_block(CW, bid - 48);
}

// ================= stats: hcl (512) + 4 cluster GEMMs ====================
__global__ __launch_bounds__(256) void stats_all(
    Descs D, const unsigned short* __restrict__ Y0b,
    const float* __restrict__ cw, const float* __restrict__ cb,
    float* __restrict__ hcl)
{
    int bid = blockIdx.x;
    if (bid < NTOK) { hcl_block(Y0b, cw, cb, hcl, bid); return; }
    int b2 = bid - NTOK;
    int ci = decode_ci(D.ofs, b2);
    int local = b2 - D.ofs[ci];
    int bx, by;
    xcd_map(local, D.c[ci].nx, bx, by);
    gemm_tile<1>(D.c[ci], bx, by, nullptr, ci);
}

// ================= apply (cache path): stream all 4 segments ============
struct ASeg { const unsigned short* L; int ldL, N, outOff, chunks, start; };
struct ADesc { ASeg s[4]; };

__global__ __launch_bounds__(256) void apply_all(
    ADesc A, const float* __restrict__ adds, float* __restrict__ out)
{
    int bid = blockIdx.x;
    int i = 3;
    #pragma unroll
    for (int k = 3; k >= 1; --k) if (bid < A.s[k].start) i = k - 1;
    const ASeg g = A.s[i];
    int local = bid - g.start;
    int t = local / g.chunks;
    int n0 = (local % g.chunks) * 2048 + threadIdx.x * 8;
    float a = adds[t * 4 + i];
    const unsigned short* Lr = g.L + (size_t)t * g.ldL;
    float* o = out + (size_t)t * VOCAB + g.outOff;
    if (n0 + 8 <= g.N) {
        ushort4 u0 = *(const ushort4*)(Lr + n0);
        ushort4 u1 = *(const ushort4*)(Lr + n0 + 4);
        float4 f0, f1;
        f0.x = bf2f(u0.x) + a; f0.y = bf2f(u0.y) + a;
        f0.z = bf2f(u0.z) + a; f0.w = bf2f(u0.w) + a;
        f1.x = bf2f(u1.x) + a; f1.y = bf2f(u1.y) + a;
        f1.z = bf2f(u1.z) + a; f1.w = bf2f(u1.w) + a;
        *(float4*)(o + n0) = f0;
        *(float4*)(o + n0 + 4) = f1;
    } else {
        #pragma unroll
        for (int j = 0; j < 8; ++j) {
            int n = n0 + j;
            if (n < g.N) o[n] = bf2f(Lr[n]) + a;
        }
    }
}

// ================= write (fallback path): head apply + tail GEMMs ========
__global__ __launch_bounds__(256) void write_all(
    Descs D, const float* __restrict__ adds,
    const unsigned short* __restrict__ L0, float* __restrict__ out,
    int applyBlocks)
{
    int bid = blockIdx.x;
    if (bid < applyBlocks) {
        int idx8 = bid * 256 + threadIdx.x;
        int t = idx8 / 2500;
        int n = (idx8 % 2500) * 8;
        float a0 = adds[t * 4 + 0];
        ushort4 u0 = *(const ushort4*)(L0 + (size_t)t * 20096 + n);
        ushort4 u1 = *(const ushort4*)(L0 + (size_t)t * 20096 + n + 4);
        float* o = out + (size_t)t * VOCAB + n;
        float4 f0, f1;
        f0.x = bf2f(u0.x) + a0; f0.y = bf2f(u0.y) + a0;
        f0.z = bf2f(u0.z) + a0; f0.w = bf2f(u0.w) + a0;
        f1.x = bf2f(u1.x) + a0; f1.y = bf2f(u1.y) + a0;
        f1.z = bf2f(u1.z) + a0; f1.w = bf2f(u1.w) + a0;
        *(float4*)o = f0; *(float4*)(o + 4) = f1;
        return;
    }
    int b2 = bid - applyBlocks;
    int ci = 1;
    #pragma unroll
    for (int i = 2; i < 4; ++i) if (b2 >= D.ofs[i]) ci = i;
    int local = b2 - D.ofs[ci];
    int bx, by;
    xcd_map(local, D.c[ci].nx, bx, by);
    gemm_tile<2>(D.c[ci], bx, by, adds, ci);
}

// ---------------- reduce partials + finish ----------------
__device__ __forceinline__ float blk_sum(float v, float* sm) {
    #pragma unroll
    for (int off = 32; off > 0; off >>= 1) v += __shfl_down(v, off, 64);
    int wid = threadIdx.x >> 6, lane = threadIdx.x & 63;
    if (lane == 0) sm[wid] = v;
    __syncthreads();
    float r = 0.f;
    if (threadIdx.x == 0) {
        for (int i = 0; i < 4; ++i) r += sm[i];
        sm[4] = r;
    }
    __syncthreads();
    r = sm[4];
    __syncthreads();
    return r;
}

__global__ __launch_bounds__(256) void reduce_finish(
    const float* __restrict__ p0, const float* __restrict__ p1,
    const float* __restrict__ p2, const float* __restrict__ p3,
    const float* __restrict__ hcl, float* __restrict__ adds,
    int n0, int n1, int n2, int n3)
{
    __shared__ float sm[8];
    const int t = blockIdx.x;
    const float* ps[4] = {p0 + (size_t)t * n0, p1 + (size_t)t * n1,
                          p2 + (size_t)t * n2, p3 + (size_t)t * n3};
    const int nn[4] = {n0, n1, n2, n3};
    float s[4];
    #pragma unroll
    for (int i = 0; i < 4; ++i) {
        float v = 0.f;
        for (int j = threadIdx.x; j < nn[i]; j += 256) v += ps[i][j];
        s[i] = blk_sum(v, sm);
    }
    if (threadIdx.x == 0) {
        float h0 = hcl[t * 3 + 0], h1 = hcl[t * 3 + 1], h2 = hcl[t * 3 + 2];
        float lse_head = __logf(s[0] + __expf(h0) + __expf(h1) + __expf(h2));
        adds[t * 4 + 0] = -lse_head;
        adds[t * 4 + 1] = (h0 - lse_head) - __logf(s[1]);
        adds[t * 4 + 2] = (h1 - lse_head) - __logf(s[2]);
        adds[t * 4 + 3] = (h2 - lse_head) - __logf(s[3]);
    }
}

// ---------------- loss ----------------
__global__ __launch_bounds__(512) void loss_kernel(
    const float* __restrict__ out, const int* __restrict__ target,
    float* __restrict__ loss)
{
    __shared__ float sm[8];
    const int t = threadIdx.x;
    float v = -out[(size_t)t * VOCAB + target[t]];
    #pragma unroll
    for (int off = 32; off > 0; off >>= 1) v += __shfl_down(v, off, 64);
    int wid = threadIdx.x >> 6, lane = threadIdx.x & 63;
    if (lane == 0) sm[wid] = v;
    __syncthreads();
    if (threadIdx.x == 0) {
        float s = 0.f;
        for (int i = 0; i < 8; ++i) s += sm[i];
        *loss = s / (float)NTOK;
    }
}

// ---------------- launch ----------------
extern "C" void kernel_launch(void* const* d_in, const int* in_sizes, int n_in,
                              void* d_out, int out_size, void* d_ws, size_t ws_size,
                              hipStream_t stream)
{
    const float* hidden = (const float*)d_in[0];
    const int*   target = (const int*)d_in[1];
    const float* cw     = (const float*)d_in[2];
    const float* cb     = (const float*)d_in[3];
    const float* proj[4] = {(const float*)d_in[4], (const float*)d_in[7],
                            (const float*)d_in[10], (const float*)d_in[13]};
    const float* W[4]    = {(const float*)d_in[5], (const float*)d_in[8],
                            (const float*)d_in[11], (const float*)d_in[14]};
    const float* b[4]    = {(const float*)d_in[6], (const float*)d_in[9],
                            (const float*)d_in[12], (const float*)d_in[15]};
    float* out = (float*)d_out;
    char*  w8  = (char*)d_ws;
    dim3 blk(256);

    const int nx0 = 157, nx1 = 157, nx2 = 1250, nx3 = 530;

    // ---- workspace layout: r12 prefix first (fallback-compatible), LC1-3 last ----
    size_t off = 0;
    auto alloc = [&](size_t bytes) { size_t o = off; off += (bytes + 255) & ~(size_t)255; return o; };
    size_t oHb  = alloc((size_t)512 * 1024 * 2);
    size_t oY0  = alloc((size_t)512 * 1024 * 2);
    size_t oY1  = alloc((size_t)512 * 256 * 2);
    size_t oY2  = alloc((size_t)512 * 64 * 2);
    size_t oY3  = alloc((size_t)512 * 32 * 2);
    size_t ohcl = alloc((size_t)512 * 3 * 4);
    size_t oadd = alloc((size_t)512 * 4 * 4);
    size_t oL0  = alloc((size_t)512 * 20096 * 2);     // head logit cache (both paths)
    size_t oPS0 = alloc((size_t)512 * (2 * nx0) * 4);
    size_t oPS1 = alloc((size_t)512 * (2 * nx1) * 4);
    size_t oPS2 = alloc((size_t)512 * (2 * nx2) * 4);
    size_t oPS3 = alloc((size_t)512 * (2 * nx3) * 4);
    size_t oP0  = alloc((size_t)1024 * 1024 * 2);
    size_t oP1  = alloc((size_t)256 * 1024 * 2);
    size_t oP2  = alloc((size_t)128 * 1024 * 2);
    size_t oP3  = alloc((size_t)128 * 1024 * 2);
    size_t oW0  = alloc((size_t)20096 * 1024 * 2);
    size_t oW1  = alloc((size_t)20096 * 256 * 2);
    size_t oW2  = alloc((size_t)160000 * 64 * 2);
    size_t oW3  = alloc((size_t)67840 * 32 * 2);
    // tail logit caches (cache path only)
    size_t oL1  = alloc((size_t)512 * 20096 * 2);
    size_t oL2  = alloc((size_t)512 * 160000 * 2);
    size_t oL3  = alloc((size_t)512 * 67840 * 2);
    size_t need_full = off;
    const bool cachePath = (ws_size >= need_full);

    unsigned short* Hb  = (unsigned short*)(w8 + oHb);
    unsigned short* Y0b = (unsigned short*)(w8 + oY0);
    unsigned short* Y1b = (unsigned short*)(w8 + oY1);
    unsigned short* Y2b = (unsigned short*)(w8 + oY2);
    unsigned short* Y3p = (unsigned short*)(w8 + oY3);
    float* hcl  = (float*)(w8 + ohcl);
    float* adds = (float*)(w8 + oadd);
    unsigned short* L0 = (unsigned short*)(w8 + oL0);
    float* PS0  = (float*)(w8 + oPS0);
    float* PS1  = (float*)(w8 + oPS1);
    float* PS2  = (float*)(w8 + oPS2);
    float* PS3  = (float*)(w8 + oPS3);
    unsigned short* P0a = (unsigned short*)(w8 + oP0);
    unsigned short* P1a = (unsigned short*)(w8 + oP1);
    unsigned short* P2a = (unsigned short*)(w8 + oP2);
    unsigned short* P3a = (unsigned short*)(w8 + oP3);
    unsigned short* W0a = (unsigned short*)(w8 + oW0);
    unsigned short* W1a = (unsigned short*)(w8 + oW1);
    unsigned short* W2a = (unsigned short*)(w8 + oW2);
    unsigned short* W3a = (unsigned short*)(w8 + oW3);
    unsigned short* L1 = (unsigned short*)(w8 + oL1);
    unsigned short* L2 = (unsigned short*)(w8 + oL2);
    unsigned short* L3 = (unsigned short*)(w8 + oL3);

    // ---- launch 1: convert H + 4 projs (1024 blocks) ----
    Conv9 CS;
    CS.d[0] = {hidden,  Hb,  512,  1024, 512,  1024};
    CS.d[1] = {proj[0], P0a, 1024, 1024, 1024, 1024};
    CS.d[2] = {proj[1], P1a, 256,  1024, 256,  1024};
    CS.d[3] = {proj[2], P2a, 64,   1024, 128,  1024};
    CS.d[4] = {proj[3], P3a, 16,   1024, 128,  1024};
    CS.start[0] = 0; CS.start[1] = 256; CS.start[2] = 768; CS.start[3] = 896; CS.start[4] = 960;
    for (int i = 5; i < 9; ++i) { CS.d[i] = CS.d[4]; CS.start[i] = BIGSTART; }
    conv_all<<<1024, blk, 0, stream>>>(CS);

    // ---- launch 2: mega = proj GEMMs (48) + W conversions (exactly 18620) ----
    Descs PD;
    PD.c[0] = {Hb, P0a, nullptr, nullptr, Y0b, nullptr, 1024, 1024, 1024, 1024, 8, 0, 1024};
    PD.c[1] = {Hb, P1a, nullptr, nullptr, Y1b, nullptr, 1024, 1024, 256,  1024, 2, 0, 256};
    PD.c[2] = {Hb, P2a, nullptr, nullptr, Y2b, nullptr, 1024, 1024, 64,   1024, 1, 0, 64};
    PD.c[3] = {Hb, P3a, nullptr, nullptr, Y3p, nullptr, 1024, 1024, 16,   1024, 1, 0, 32};
    PD.ofs[0] = 0; PD.ofs[1] = 32; PD.ofs[2] = 40; PD.ofs[3] = 44;
    Conv9 CW;
    CW.d[0] = {W[0], W0a, 20000,  1024, 20096,  1024};
    CW.d[1] = {W[1], W1a, 20000,  256,  20096,  256};
    CW.d[2] = {W[2], W2a, 160000, 64,   160000, 64};
    CW.d[3] = {W[3], W3a, 67735,  16,   67840,  32};
    CW.start[0] = 0; CW.start[1] = 10048; CW.start[2] = 12560; CW.start[3] = 17560;
    for (int i = 4; i < 9; ++i) { CW.d[i] = CW.d[3]; CW.start[i] = BIGSTART; }
    mega_projconv<<<48 + 18620, blk, 0, stream>>>(PD, CW);

    // ---- launch 3: stats (hcl + 4 clusters; cache path caches ALL logits) ----
    Descs SD;
    SD.c[0] = {Y0b, W0a, b[0], PS0, L0, nullptr, 1024, 1024, 20000,  1024, nx0, 2*nx0, 20096};
    SD.c[1] = {Y1b, W1a, b[1], PS1, cachePath ? L1 : nullptr, nullptr, 256, 256, 20000, 256, nx1, 2*nx1, 20096};
    SD.c[2] = {Y2b, W2a, b[2], PS2, cachePath ? L2 : nullptr, nullptr, 64, 64, 160000, 64, nx2, 2*nx2, 160000};
    SD.c[3] = {Y3p, W3a, b[3], PS3, cachePath ? L3 : nullptr, nullptr, 32, 32, 67735, 32, nx3, 2*nx3, 67840};
    SD.ofs[0] = 0; SD.ofs[1] = 4*nx0; SD.ofs[2] = 4*(nx0+nx1); SD.ofs[3] = 4*(nx0+nx1+nx2);
    stats_all<<<NTOK + 4*(nx0+nx1+nx2+nx3), blk, 0, stream>>>(SD, Y0b, cw, cb, hcl);

    // ---- launch 4: reduce + finish ----
    reduce_finish<<<NTOK, blk, 0, stream>>>(PS0, PS1, PS2, PS3, hcl, adds,
                                            2*nx0, 2*nx1, 2*nx2, 2*nx3);

    // ---- launch 5: write ----
    if (cachePath) {
        // pure streaming apply over all 4 segments
        ADesc AD;
        AD.s[0] = {L0, 20096,  20000,  0,      10, 0};
        AD.s[1] = {L1, 20096,  20000,  20000,  10, 5120};
        AD.s[2] = {L2, 160000, 160000, 40000,  79, 10240};
        AD.s[3] = {L3, 67840,  67735,  200000, 34, 50688};
        apply_all<<<68096, blk, 0, stream>>>(AD, adds, out);
    } else {
        Descs WD;
        WD.c[0] = SD.c[0];   // unused
        WD.c[1] = {Y1b, W1a, b[1], nullptr, nullptr, out + 20000,  256, 256, 20000,  256, nx1, 0, 0};
        WD.c[2] = {Y2b, W2a, b[2], nullptr, nullptr, out + 40000,  64,  64,  160000, 64,  nx2, 0, 0};
        WD.c[3] = {Y3p, W3a, b[3], nullptr, nullptr, out + 200000, 32,  32,  67735,  32,  nx3, 0, 0};
        WD.ofs[0] = 0; WD.ofs[1] = 0; WD.ofs[2] = 4*nx1; WD.ofs[3] = 4*(nx1+nx2);
        const int applyBlocks = 5000;
        write_all<<<applyBlocks + 4*(nx1+nx2+nx3), blk, 0, stream>>>(WD, adds, L0, out, applyBlocks);
    }

    // ---- launch 6: loss ----
    loss_kernel<<<1, NTOK, 0, stream>>>(out, target, out + (size_t)NTOK * VOCAB);
}

// Round 17
// 376.061 us; speedup vs baseline: 2.0787x; 1.0489x over previous
//
#include <hip/hip_runtime.h>
#include <math.h>

#define VOCAB 267735
#define NTOK  512
#define CDIV(a,b) (((a)+(b)-1)/(b))
#define BIGSTART 0x7fffffff

typedef __bf16 bf16x8 __attribute__((ext_vector_type(8)));
typedef float f32x4 __attribute__((ext_vector_type(4)));
typedef const __attribute__((address_space(1))) void* gas_ptr;
typedef __attribute__((address_space(3))) void* las_ptr;

__device__ __forceinline__ unsigned short f2bf(float x) {
    unsigned int u = __float_as_uint(x);
    u = (u + 0x7FFFu + ((u >> 16) & 1u)) >> 16;
    return (unsigned short)u;
}
__device__ __forceinline__ float bf2f(unsigned short h) {
    return __uint_as_float(((unsigned int)h) << 16);
}
__device__ __forceinline__ void gload_lds16(const void* g, void* l) {
    __builtin_amdgcn_global_load_lds((gas_ptr)g, (las_ptr)l, 16, 0, 0);
}

// ================= fp32->bf16 conversion block (shared device body) =================
struct ConvDesc { const float* src; unsigned short* dst; int nrows, kb, npad, ldb; };
struct Conv9 { ConvDesc d[9]; int start[9]; };

__device__ __forceinline__ void conv_block(const Conv9& C, int bid)
{
    int i = 8;
    #pragma unroll
    for (int k = 8; k >= 1; --k) if (bid < C.start[k]) i = k - 1;
    const ConvDesc d = C.d[i];
    int local = bid - C.start[i];
    int idx8 = local * 256 + threadIdx.x;
    int ld8 = d.ldb / 8;
    int r  = idx8 / ld8;
    int c8 = (idx8 % ld8) * 8;
    ushort4 o0 = {0,0,0,0}, o1 = {0,0,0,0};
    if (r < d.nrows && c8 < d.kb) {
        const float* s = d.src + (size_t)r * d.kb + c8;
        float4 f0 = *(const float4*)s;
        float4 f1 = *(const float4*)(s + 4);
        o0.x = f2bf(f0.x); o0.y = f2bf(f0.y); o0.z = f2bf(f0.z); o0.w = f2bf(f0.w);
        o1.x = f2bf(f1.x); o1.y = f2bf(f1.y); o1.z = f2bf(f1.z); o1.w = f2bf(f1.w);
    }
    ushort4* dd = (ushort4*)(d.dst + (size_t)r * d.ldb + c8);
    dd[0] = o0; dd[1] = o1;
}

__global__ __launch_bounds__(256) void conv_all(Conv9 C) { conv_block(C, blockIdx.x); }

// ================= GEMM tile core: BM=BN=128, BK=32, DOUBLE-buffered 2-phase ============
// T3 minimal 2-phase (r7-validated barrier pattern): STAGE(next); COMPUTE(cur);
// fused "s_waitcnt vmcnt(0); s_barrier" once per K-step. Next-tile loads issued
// BEFORE current compute -> HBM latency hides under the 16 MFMAs. LDS 32 KB.
struct CDesc {
    const unsigned short* A;   // [512][lda] bf16
    const unsigned short* Bb;  // [Npad][ldb] bf16 arena, pads zero
    const float* bias;
    float* psum;
    unsigned short* L;         // bf16 logit cache (nullable)
    float* Cout;
    int lda, ldb, N, K, nx, pstride, ldL;
};
struct Descs { CDesc c[4]; int ofs[4]; };

// XCD-aware intra-cluster mapping (neutral, harmless)
__device__ __forceinline__ void xcd_map(int local, int nx, int& bx, int& by)
{
    int q = nx >> 3, r = nx & 7;
    if (local < 32 * q) {
        bx = ((local >> 5) << 3) + (local & 7);
        by = (local >> 3) & 3;
    } else {
        int t = local - 32 * q;
        bx = (q << 3) + t % r;
        by = t / r;
    }
}

// MODE 0: L[gm*ldL+gn]=bf16(acc), gn<ldL
// MODE 1: psum[gm*pstride+2*bx+wn]=sum_{gn<N} exp(acc+bias); if L: L[..]=bf16(acc+bias)
// MODE 2: Cout[gm*VOCAB+gn]=acc+bias[gn]+adds[gm*4+ci]
template<int MODE>
__device__ __forceinline__ void gemm_tile(const CDesc& d, int bx, int by,
                                          const float* adds, int ci)
{
    __shared__ unsigned short As[2][128 * 32];   // 16 KB
    __shared__ unsigned short Bs[2][128 * 32];   // 16 KB
    const int tid  = threadIdx.x;
    const int lane = tid & 63;
    const int w    = tid >> 6;
    const int wm   = w >> 1, wn = w & 1;
    const int mBase = by * 128;
    const int nBase = bx * 128;
    const int col = lane & 15, rg = lane >> 4;

    f32x4 acc[4][4] = {};

    auto STAGE = [&](int buf, int k0) {
        #pragma unroll
        for (int i = 0; i < 2; ++i) {
            int c = tid + i * 256;
            int m = c >> 2, k8 = (c & 3) * 8;
            gload_lds16(d.A + (size_t)(mBase + m) * d.lda + k0 + k8, &As[buf][(size_t)c * 8]);
        }
        #pragma unroll
        for (int i = 0; i < 2; ++i) {
            int c = tid + i * 256;
            int n = c >> 2, k8 = (c & 3) * 8;
            gload_lds16(d.Bb + (size_t)(nBase + n) * d.ldb + k0 + k8, &Bs[buf][(size_t)c * 8]);
        }
    };

    auto COMPUTE = [&](int buf) {
        bf16x8 af[4], bfr[4];
        #pragma unroll
        for (int mi = 0; mi < 4; ++mi)
            af[mi] = *(const bf16x8*)&As[buf][(wm * 64 + mi * 16 + col) * 32 + rg * 8];
        #pragma unroll
        for (int ni = 0; ni < 4; ++ni)
            bfr[ni] = *(const bf16x8*)&Bs[buf][(wn * 64 + ni * 16 + col) * 32 + rg * 8];
        #pragma unroll
        for (int mi = 0; mi < 4; ++mi)
            #pragma unroll
            for (int ni = 0; ni < 4; ++ni)
                acc[mi][ni] = __builtin_amdgcn_mfma_f32_16x16x32_bf16(
                    af[mi], bfr[ni], acc[mi][ni], 0, 0, 0);
    };

    const int nt = d.K >> 5;
    STAGE(0, 0);
    asm volatile("s_waitcnt vmcnt(0)\n\ts_barrier" ::: "memory");
    int cur = 0;
    for (int t = 0; t < nt - 1; ++t) {
        STAGE(cur ^ 1, (t + 1) << 5);   // next-tile loads in flight during compute
        COMPUTE(cur);
        asm volatile("s_waitcnt vmcnt(0)\n\ts_barrier" ::: "memory");
        cur ^= 1;
    }
    COMPUTE(cur);

    if (MODE == 1) {
        const bool hasL = (d.L != nullptr);
        const int bx2 = bx * 2 + wn;
        #pragma unroll
        for (int mi = 0; mi < 4; ++mi) {
            int gm = mBase + wm * 64 + mi * 16 + rg * 4;
            float part[4] = {0.f, 0.f, 0.f, 0.f};
            #pragma unroll
            for (int ni = 0; ni < 4; ++ni) {
                int gn = nBase + wn * 64 + ni * 16 + col;
                float bvv = (gn < d.N) ? d.bias[gn] : 0.f;
                #pragma unroll
                for (int r = 0; r < 4; ++r) {
                    float v = acc[mi][ni][r] + bvv;
                    if (gn < d.N) part[r] += __expf(v);
                    if (hasL) d.L[(size_t)(gm + r) * d.ldL + gn] = f2bf(v);
                }
            }
            #pragma unroll
            for (int r = 0; r < 4; ++r) {
                float v = part[r];
                #pragma unroll
                for (int s = 8; s >= 1; s >>= 1) v += __shfl_xor(v, s, 16);
                if (col == 0)
                    d.psum[(size_t)(gm + r) * d.pstride + bx2] = v;
            }
        }
    } else if (MODE == 2) {
        #pragma unroll
        for (int mi = 0; mi < 4; ++mi) {
            int gm = mBase + wm * 64 + mi * 16 + rg * 4;
            float av[4];
            #pragma unroll
            for (int r = 0; r < 4; ++r) av[r] = adds[(gm + r) * 4 + ci];
            #pragma unroll
            for (int ni = 0; ni < 4; ++ni) {
                int gn = nBase + wn * 64 + ni * 16 + col;
                if (gn < d.N) {
                    float bvv = d.bias[gn];
                    #pragma unroll
                    for (int r = 0; r < 4; ++r)
                        d.Cout[(size_t)(gm + r) * VOCAB + gn] = acc[mi][ni][r] + bvv + av[r];
                }
            }
        }
    } else {
        #pragma unroll
        for (int mi = 0; mi < 4; ++mi) {
            int gm = mBase + wm * 64 + mi * 16 + rg * 4;
            #pragma unroll
            for (int ni = 0; ni < 4; ++ni) {
                int gn = nBase + wn * 64 + ni * 16 + col;
                if (gn < d.ldL) {
                    #pragma unroll
                    for (int r = 0; r < 4; ++r)
                        d.L[(size_t)(gm + r) * d.ldL + gn] = f2bf(acc[mi][ni][r]);
                }
            }
        }
    }
}

__device__ __forceinline__ int decode_ci(const int* ofs, int bid) {
    int ci = 0;
    #pragma unroll
    for (int i = 1; i < 4; ++i) if (bid >= ofs[i]) ci = i;
    return ci;
}

// ---------------- cluster logits ----------------
__device__ __forceinline__ void hcl_block(
    const unsigned short* Y0b, const float* cw, const float* cb, float* hcl, int t)
{
    int w = threadIdx.x >> 6, l = threadIdx.x & 63;
    if (w >= 3) return;
    const unsigned short* yrow = Y0b + (size_t)t * 1024;
    float s = 0.f;
    #pragma unroll
    for (int e = 0; e < 16; ++e) {
        int k = l * 16 + e;
        s += bf2f(yrow[k]) * cw[w * 1024 + k];
    }
    #pragma unroll
    for (int off = 32; off > 0; off >>= 1) s += __shfl_down(s, off, 64);
    if (l == 0) hcl[t * 3 + w] = s + cb[w];
}

// ================= mega launch: proj GEMMs (48) + W conversion =========
__global__ __launch_bounds__(256) void mega_projconv(Descs PD, Conv9 CW)
{
    int bid = blockIdx.x;
    if (bid < 48) {
        int ci = decode_ci(PD.ofs, bid);
        int local = bid - PD.ofs[ci];
        gemm_tile<0>(PD.c[ci], local % PD.c[ci].nx, local / PD.c[ci].nx, nullptr, ci);
        return;
    }
    conv_block(CW, bid - 48);
}

// ================= stats: hcl (512) + 4 cluster GEMMs ====================
__global__ __launch_bounds__(256) void stats_all(
    Descs D, const unsigned short* __restrict__ Y0b,
    const float* __restrict__ cw, const float* __restrict__ cb,
    float* __restrict__ hcl)
{
    int bid = blockIdx.x;
    if (bid < NTOK) { hcl_block(Y0b, cw, cb, hcl, bid); return; }
    int b2 = bid - NTOK;
    int ci = decode_ci(D.ofs, b2);
    int local = b2 - D.ofs[ci];
    int bx, by;
    xcd_map(local, D.c[ci].nx, bx, by);
    gemm_tile<1>(D.c[ci], bx, by, nullptr, ci);
}

// ================= write: head apply + 3 tail GEMMs ====================
__global__ __launch_bounds__(256) void write_all(
    Descs D, const float* __restrict__ adds,
    const unsigned short* __restrict__ L0, float* __restrict__ out,
    int applyBlocks)
{
    int bid = blockIdx.x;
    if (bid < applyBlocks) {
        int idx8 = bid * 256 + threadIdx.x;
        int t = idx8 / 2500;
        int n = (idx8 % 2500) * 8;
        float a0 = adds[t * 4 + 0];
        ushort4 u0 = *(const ushort4*)(L0 + (size_t)t * 20096 + n);
        ushort4 u1 = *(const ushort4*)(L0 + (size_t)t * 20096 + n + 4);
        float* o = out + (size_t)t * VOCAB + n;
        float4 f0, f1;
        f0.x = bf2f(u0.x) + a0; f0.y = bf2f(u0.y) + a0;
        f0.z = bf2f(u0.z) + a0; f0.w = bf2f(u0.w) + a0;
        f1.x = bf2f(u1.x) + a0; f1.y = bf2f(u1.y) + a0;
        f1.z = bf2f(u1.z) + a0; f1.w = bf2f(u1.w) + a0;
        *(float4*)o = f0; *(float4*)(o + 4) = f1;
        return;
    }
    int b2 = bid - applyBlocks;
    int ci = 1;
    #pragma unroll
    for (int i = 2; i < 4; ++i) if (b2 >= D.ofs[i]) ci = i;
    int local = b2 - D.ofs[ci];
    int bx, by;
    xcd_map(local, D.c[ci].nx, bx, by);
    gemm_tile<2>(D.c[ci], bx, by, adds, ci);
}

// ---------------- reduce partials + finish ----------------
__device__ __forceinline__ float blk_sum(float v, float* sm) {
    #pragma unroll
    for (int off = 32; off > 0; off >>= 1) v += __shfl_down(v, off, 64);
    int wid = threadIdx.x >> 6, lane = threadIdx.x & 63;
    if (lane == 0) sm[wid] = v;
    __syncthreads();
    float r = 0.f;
    if (threadIdx.x == 0) {
        for (int i = 0; i < 4; ++i) r += sm[i];
        sm[4] = r;
    }
    __syncthreads();
    r = sm[4];
    __syncthreads();
    return r;
}

__global__ __launch_bounds__(256) void reduce_finish(
    const float* __restrict__ p0, const float* __restrict__ p1,
    const float* __restrict__ p2, const float* __restrict__ p3,
    const float* __restrict__ hcl, float* __restrict__ adds,
    int n0, int n1, int n2, int n3)
{
    __shared__ float sm[8];
    const int t = blockIdx.x;
    const float* ps[4] = {p0 + (size_t)t * n0, p1 + (size_t)t * n1,
                          p2 + (size_t)t * n2, p3 + (size_t)t * n3};
    const int nn[4] = {n0, n1, n2, n3};
    float s[4];
    #pragma unroll
    for (int i = 0; i < 4; ++i) {
        float v = 0.f;
        for (int j = threadIdx.x; j < nn[i]; j += 256) v += ps[i][j];
        s[i] = blk_sum(v, sm);
    }
    if (threadIdx.x == 0) {
        float h0 = hcl[t * 3 + 0], h1 = hcl[t * 3 + 1], h2 = hcl[t * 3 + 2];
        float lse_head = __logf(s[0] + __expf(h0) + __expf(h1) + __expf(h2));
        adds[t * 4 + 0] = -lse_head;
        adds[t * 4 + 1] = (h0 - lse_head) - __logf(s[1]);
        adds[t * 4 + 2] = (h1 - lse_head) - __logf(s[2]);
        adds[t * 4 + 3] = (h2 - lse_head) - __logf(s[3]);
    }
}

// ---------------- loss ----------------
__global__ __launch_bounds__(512) void loss_kernel(
    const float* __restrict__ out, const int* __restrict__ target,
    float* __restrict__ loss)
{
    __shared__ float sm[8];
    const int t = threadIdx.x;
    float v = -out[(size_t)t * VOCAB + target[t]];
    #pragma unroll
    for (int off = 32; off > 0; off >>= 1) v += __shfl_down(v, off, 64);
    int wid = threadIdx.x >> 6, lane = threadIdx.x & 63;
    if (lane == 0) sm[wid] = v;
    __syncthreads();
    if (threadIdx.x == 0) {
        float s = 0.f;
        for (int i = 0; i < 8; ++i) s += sm[i];
        *loss = s / (float)NTOK;
    }
}

// ---------------- launch ----------------
extern "C" void kernel_launch(void* const* d_in, const int* in_sizes, int n_in,
                              void* d_out, int out_size, void* d_ws, size_t ws_size,
                              hipStream_t stream)
{
    const float* hidden = (const float*)d_in[0];
    const int*   target = (const int*)d_in[1];
    const float* cw     = (const float*)d_in[2];
    const float* cb     = (const float*)d_in[3];
    const float* proj[4] = {(const float*)d_in[4], (const float*)d_in[7],
                            (const float*)d_in[10], (const float*)d_in[13]};
    const float* W[4]    = {(const float*)d_in[5], (const float*)d_in[8],
                            (const float*)d_in[11], (const float*)d_in[14]};
    const float* b[4]    = {(const float*)d_in[6], (const float*)d_in[9],
                            (const float*)d_in[12], (const float*)d_in[15]};
    float* out = (float*)d_out;
    char*  w8  = (char*)d_ws;
    dim3 blk(256);

    const int nx0 = 157, nx1 = 157, nx2 = 1250, nx3 = 530;

    // ---- workspace layout (r12) ----
    size_t off = 0;
    auto alloc = [&](size_t bytes) { size_t o = off; off += (bytes + 255) & ~(size_t)255; return o; };
    size_t oHb  = alloc((size_t)512 * 1024 * 2);
    size_t oY0  = alloc((size_t)512 * 1024 * 2);
    size_t oY1  = alloc((size_t)512 * 256 * 2);
    size_t oY2  = alloc((size_t)512 * 64 * 2);
    size_t oY3  = alloc((size_t)512 * 32 * 2);
    size_t ohcl = alloc((size_t)512 * 3 * 4);
    size_t oadd = alloc((size_t)512 * 4 * 4);
    size_t oL0  = alloc((size_t)512 * 20096 * 2);
    size_t oPS0 = alloc((size_t)512 * (2 * nx0) * 4);
    size_t oPS1 = alloc((size_t)512 * (2 * nx1) * 4);
    size_t oPS2 = alloc((size_t)512 * (2 * nx2) * 4);
    size_t oPS3 = alloc((size_t)512 * (2 * nx3) * 4);
    size_t oP0  = alloc((size_t)1024 * 1024 * 2);
    size_t oP1  = alloc((size_t)256 * 1024 * 2);
    size_t oP2  = alloc((size_t)128 * 1024 * 2);
    size_t oP3  = alloc((size_t)128 * 1024 * 2);
    size_t oW0  = alloc((size_t)20096 * 1024 * 2);
    size_t oW1  = alloc((size_t)20096 * 256 * 2);
    size_t oW2  = alloc((size_t)160000 * 64 * 2);
    size_t oW3  = alloc((size_t)67840 * 32 * 2);

    unsigned short* Hb  = (unsigned short*)(w8 + oHb);
    unsigned short* Y0b = (unsigned short*)(w8 + oY0);
    unsigned short* Y1b = (unsigned short*)(w8 + oY1);
    unsigned short* Y2b = (unsigned short*)(w8 + oY2);
    unsigned short* Y3p = (unsigned short*)(w8 + oY3);
    float* hcl  = (float*)(w8 + ohcl);
    float* adds = (float*)(w8 + oadd);
    unsigned short* L0 = (unsigned short*)(w8 + oL0);
    float* PS0  = (float*)(w8 + oPS0);
    float* PS1  = (float*)(w8 + oPS1);
    float* PS2  = (float*)(w8 + oPS2);
    float* PS3  = (float*)(w8 + oPS3);
    unsigned short* P0a = (unsigned short*)(w8 + oP0);
    unsigned short* P1a = (unsigned short*)(w8 + oP1);
    unsigned short* P2a = (unsigned short*)(w8 + oP2);
    unsigned short* P3a = (unsigned short*)(w8 + oP3);
    unsigned short* W0a = (unsigned short*)(w8 + oW0);
    unsigned short* W1a = (unsigned short*)(w8 + oW1);
    unsigned short* W2a = (unsigned short*)(w8 + oW2);
    unsigned short* W3a = (unsigned short*)(w8 + oW3);

    // ---- launch 1: convert H + 4 projs (1024 blocks) ----
    Conv9 CS;
    CS.d[0] = {hidden,  Hb,  512,  1024, 512,  1024};
    CS.d[1] = {proj[0], P0a, 1024, 1024, 1024, 1024};
    CS.d[2] = {proj[1], P1a, 256,  1024, 256,  1024};
    CS.d[3] = {proj[2], P2a, 64,   1024, 128,  1024};
    CS.d[4] = {proj[3], P3a, 16,   1024, 128,  1024};
    CS.start[0] = 0; CS.start[1] = 256; CS.start[2] = 768; CS.start[3] = 896; CS.start[4] = 960;
    for (int i = 5; i < 9; ++i) { CS.d[i] = CS.d[4]; CS.start[i] = BIGSTART; }
    conv_all<<<1024, blk, 0, stream>>>(CS);

    // ---- launch 2: mega = proj GEMMs (48) + W conversions (18620) ----
    Descs PD;
    PD.c[0] = {Hb, P0a, nullptr, nullptr, Y0b, nullptr, 1024, 1024, 1024, 1024, 8, 0, 1024};
    PD.c[1] = {Hb, P1a, nullptr, nullptr, Y1b, nullptr, 1024, 1024, 256,  1024, 2, 0, 256};
    PD.c[2] = {Hb, P2a, nullptr, nullptr, Y2b, nullptr, 1024, 1024, 64,   1024, 1, 0, 64};
    PD.c[3] = {Hb, P3a, nullptr, nullptr, Y3p, nullptr, 1024, 1024, 16,   1024, 1, 0, 32};
    PD.ofs[0] = 0; PD.ofs[1] = 32; PD.ofs[2] = 40; PD.ofs[3] = 44;
    Conv9 CW;
    CW.d[0] = {W[0], W0a, 20000,  1024, 20096,  1024};
    CW.d[1] = {W[1], W1a, 20000,  256,  20096,  256};
    CW.d[2] = {W[2], W2a, 160000, 64,   160000, 64};
    CW.d[3] = {W[3], W3a, 67735,  16,   67840,  32};
    CW.start[0] = 0; CW.start[1] = 10048; CW.start[2] = 12560; CW.start[3] = 17560;
    for (int i = 4; i < 9; ++i) { CW.d[i] = CW.d[3]; CW.start[i] = BIGSTART; }
    mega_projconv<<<48 + 18620, blk, 0, stream>>>(PD, CW);

    // ---- launch 3: stats (hcl + 4 clusters) ----
    Descs SD;
    SD.c[0] = {Y0b, W0a, b[0], PS0, L0,      nullptr, 1024, 1024, 20000,  1024, nx0, 2*nx0, 20096};
    SD.c[1] = {Y1b, W1a, b[1], PS1, nullptr, nullptr, 256,  256,  20000,  256,  nx1, 2*nx1, 0};
    SD.c[2] = {Y2b, W2a, b[2], PS2, nullptr, nullptr, 64,   64,   160000, 64,   nx2, 2*nx2, 0};
    SD.c[3] = {Y3p, W3a, b[3], PS3, nullptr, nullptr, 32,   32,   67735,  32,   nx3, 2*nx3, 0};
    SD.ofs[0] = 0; SD.ofs[1] = 4*nx0; SD.ofs[2] = 4*(nx0+nx1); SD.ofs[3] = 4*(nx0+nx1+nx2);
    stats_all<<<NTOK + 4*(nx0+nx1+nx2+nx3), blk, 0, stream>>>(SD, Y0b, cw, cb, hcl);

    // ---- launch 4: reduce + finish ----
    reduce_finish<<<NTOK, blk, 0, stream>>>(PS0, PS1, PS2, PS3, hcl, adds,
                                            2*nx0, 2*nx1, 2*nx2, 2*nx3);

    // ---- launch 5: write (head apply + tail GEMMs) ----
    Descs WD;
    WD.c[0] = SD.c[0];   // unused
    WD.c[1] = {Y1b, W1a, b[1], nullptr, nullptr, out + 20000,  256, 256, 20000,  256, nx1, 0, 0};
    WD.c[2] = {Y2b, W2a, b[2], nullptr, nullptr, out + 40000,  64,  64,  160000, 64,  nx2, 0, 0};
    WD.c[3] = {Y3p, W3a, b[3], nullptr, nullptr, out + 200000, 32,  32,  67735,  32,  nx3, 0, 0};
    WD.ofs[0] = 0; WD.ofs[1] = 0; WD.ofs[2] = 4*nx1; WD.ofs[3] = 4*(nx1+nx2);
    const int applyBlocks = 5000;
    write_all<<<applyBlocks + 4*(nx1+nx2+nx3), blk, 0, stream>>>(WD, adds, L0, out, applyBlocks);

    // ---- launch 6: loss ----
    loss_kernel<<<1, NTOK, 0, stream>>>(out, target, out + (size_t)NTOK * VOCAB);
}